// Round 5
// baseline (109.709 us; speedup 1.0000x reference)
//
#include <hip/hip_runtime.h>
#include <hip/hip_bf16.h>

typedef __attribute__((ext_vector_type(8))) short bf16x8;
typedef __attribute__((ext_vector_type(4))) float f32x4;
typedef __attribute__((ext_vector_type(8))) unsigned short us8;
typedef __attribute__((ext_vector_type(4))) unsigned short us4;
typedef __attribute__((ext_vector_type(2))) unsigned short us2;

#define LOG2E 1.4426950408889634f

__device__ __forceinline__ unsigned short f2bf(float f) {
  union { __hip_bfloat16 h; unsigned short u; } c;
  c.h = __float2bfloat16(f);
  return c.u;
}
__device__ __forceinline__ float fast_tanh(float x) {
  float e = __builtin_amdgcn_exp2f(x * (2.0f * LOG2E));     // e^(2x)
  return 1.0f - 2.0f * __builtin_amdgcn_rcpf(e + 1.0f);
}
__device__ __forceinline__ float fast_sig(float x) {
  return __builtin_amdgcn_rcpf(1.0f + __builtin_amdgcn_exp2f(-LOG2E * x));
}

// Permuted K-layout (W1 rows permuted to match, so gather is pure aligned copies).
// Original features: e2 0-11 | e3 12-29 | e4 30-37 | con 38-43.
// k0-11 e2 | k12-15 con c0-3 (orig 38-41) | k16-23 e3t0+2pad (12-17)
// k24-31 e3t1+2pad (18-23) | k32-39 e3t2+2pad (24-29) | k40-47 e4 (30-37)
// k48-49 con c4,c5 (orig 42-43) | k50 bias(=1.0 row) | k51-63 zero
__device__ __forceinline__ int k2orig(int k) {
  if (k < 12) return k;
  if (k < 16) return 38 + (k - 12);
  if (k < 24) return (k - 16) < 6 ? 12 + (k - 16) : -1;
  if (k < 32) return (k - 24) < 6 ? 18 + (k - 24) : -1;
  if (k < 40) return (k - 32) < 6 ? 24 + (k - 32) : -1;
  if (k < 48) return 30 + (k - 40);
  if (k < 50) return 42 + (k - 48);
  if (k == 50) return 44;                 // bias row marker
  return -1;
}

struct GatherRegs { int i0, i1, i2; float2 c01, c23; };

__global__ __launch_bounds__(256, 3)
void mlp_fused(const float* __restrict__ con,
               const int* __restrict__ cat2,
               const int* __restrict__ cat3,
               const int* __restrict__ cat4,
               const float* __restrict__ emb2,
               const float* __restrict__ emb3,
               const float* __restrict__ emb4,
               const float* __restrict__ W1, const float* __restrict__ b1,
               const float* __restrict__ W2, const float* __restrict__ b2,
               const float* __restrict__ W3, const float* __restrict__ b3,
               float* __restrict__ out,
               int total_tiles, int tiles_q, int tiles_r)
{
  __shared__ unsigned short embL[128];    // bf16: e2[0,24) e3-padded[24,96) e4[96,128)
  __shared__ unsigned short Xl[64 * 72];  // 64 rows x 64k (+8 pad) bf16
  __shared__ unsigned short H1[64 * 264]; // 64 x 256 (+8) bf16
  __shared__ float Part[4][64][2];        // per-wave layer-3 partials

  const int t    = threadIdx.x;
  const int wv   = t >> 6;
  const int lane = t & 63;
  const int q    = lane >> 4;
  const int r16  = lane & 15;

  // ---- preamble: bf16 tables (e3 rows padded 6->8 with zeros) --------------
  if (t < 24) embL[t] = f2bf(emb2[t]);
  else if (t < 96) { int r = t - 24, g = r >> 3, d = r & 7;
                     embL[t] = (d < 6) ? f2bf(emb3[g * 6 + d]) : 0; }
  else if (t < 128) { int r = t - 96; embL[t] = f2bf(emb4[r]); }
  // constant K region: k50 = 1.0 (bias), k51..63 = 0
  if (t < 64) {
    us2 c2v; c2v[0] = 0x3f80; c2v[1] = 0;
    *(us2*)&Xl[t * 72 + 50] = c2v;
    us4 z4 = {0, 0, 0, 0};       *(us4*)&Xl[t * 72 + 52] = z4;
    us8 z8 = {0, 0, 0, 0, 0, 0, 0, 0}; *(us8*)&Xl[t * 72 + 56] = z8;
  }

  // ---- weight fragments (A-operand = transposed weights), once per block ---
  bf16x8 w1f[4][2];               // L1: n = wv*64 + nf*16 + r16, K=64 (permuted)
  #pragma unroll
  for (int nf = 0; nf < 4; ++nf)
    #pragma unroll
    for (int ks = 0; ks < 2; ++ks) {
      const int n = wv * 64 + nf * 16 + r16;
      bf16x8 w;
      #pragma unroll
      for (int j = 0; j < 8; ++j) {
        const int o = k2orig(ks * 32 + q * 8 + j);
        float v = (o < 0) ? 0.f : ((o == 44) ? b1[n] : W1[o * 256 + n]);
        w[j] = (short)f2bf(v);
      }
      w1f[nf][ks] = w;
    }
  bf16x8 w2f[2][8];               // L2: n = wv*32 + nf*16 + r16, K=256
  #pragma unroll
  for (int nf = 0; nf < 2; ++nf)
    #pragma unroll
    for (int ks = 0; ks < 8; ++ks) {
      const int n = wv * 32 + nf * 16 + r16;
      bf16x8 w;
      #pragma unroll
      for (int j = 0; j < 8; ++j)
        w[j] = (short)f2bf(W2[(ks * 32 + q * 8 + j) * 128 + n]);
      w2f[nf][ks] = w;
    }
  float2 w3v[2][4];               // L3 weights for this lane's h2 features
  #pragma unroll
  for (int nf = 0; nf < 2; ++nf)
    #pragma unroll
    for (int i = 0; i < 4; ++i)
      w3v[nf][i] = *(const float2*)&W3[(wv * 32 + nf * 16 + q * 4 + i) * 2];
  float b2f[2][4];
  #pragma unroll
  for (int nf = 0; nf < 2; ++nf)
    #pragma unroll
    for (int i = 0; i < 4; ++i)
      b2f[nf][i] = b2[wv * 32 + nf * 16 + q * 4 + i];
  const float b3x = b3[0], b3y = b3[1];

  // ---- pipeline helpers -----------------------------------------------------
  auto gather_load = [&](int tile, GatherRegs& gr) {
    const int g = tile * 64 + lane;
    if (wv == 0) {
      gr.i0 = cat2[g * 3]; gr.i1 = cat2[g * 3 + 1]; gr.i2 = cat2[g * 3 + 2];
      gr.c01 = *(const float2*)&con[g * 6];
      gr.c23 = *(const float2*)&con[g * 6 + 2];
    } else if (wv == 1) {
      gr.i0 = cat3[g * 3]; gr.i1 = cat3[g * 3 + 1];
    } else if (wv == 2) {
      gr.i0 = cat3[g * 3 + 2]; gr.i1 = cat4[g];
    } else {
      gr.c01 = *(const float2*)&con[g * 6 + 4];
    }
  };
  auto gather_write = [&](const GatherRegs& gr) {
    unsigned short* xr = &Xl[lane * 72];
    if (wv == 0) {
      *(us4*)&xr[0] = *(const us4*)&embL[gr.i0 * 4];
      *(us4*)&xr[4] = *(const us4*)&embL[8 + gr.i1 * 4];
      *(us4*)&xr[8] = *(const us4*)&embL[16 + gr.i2 * 4];
      us4 c; c[0] = f2bf(gr.c01.x); c[1] = f2bf(gr.c01.y);
             c[2] = f2bf(gr.c23.x); c[3] = f2bf(gr.c23.y);
      *(us4*)&xr[12] = c;
    } else if (wv == 1) {
      *(us8*)&xr[16] = *(const us8*)&embL[24 + gr.i0 * 8];
      *(us8*)&xr[24] = *(const us8*)&embL[48 + gr.i1 * 8];
    } else if (wv == 2) {
      *(us8*)&xr[32] = *(const us8*)&embL[72 + gr.i0 * 8];
      *(us8*)&xr[40] = *(const us8*)&embL[96 + gr.i1 * 8];
    } else {
      us2 c; c[0] = f2bf(gr.c01.x); c[1] = f2bf(gr.c01.y);
      *(us2*)&xr[48] = c;
    }
  };
  auto layer1 = [&]() {            // Xl -> H1 (tanh), mf-sliced for reg pressure
    #pragma unroll
    for (int mf = 0; mf < 4; ++mf) {
      f32x4 acc[4];
      #pragma unroll
      for (int nf = 0; nf < 4; ++nf) acc[nf] = (f32x4){0.f, 0.f, 0.f, 0.f};
      #pragma unroll
      for (int ks = 0; ks < 2; ++ks) {
        bf16x8 xb = *(const bf16x8*)&Xl[(mf * 16 + r16) * 72 + ks * 32 + q * 8];
        #pragma unroll
        for (int nf = 0; nf < 4; ++nf)
          acc[nf] = __builtin_amdgcn_mfma_f32_16x16x32_bf16(
              w1f[nf][ks], xb, acc[nf], 0, 0, 0);
      }
      #pragma unroll
      for (int nf = 0; nf < 4; ++nf) {
        us4 o;
        #pragma unroll
        for (int i = 0; i < 4; ++i) o[i] = f2bf(fast_tanh(acc[nf][i]));
        *(us4*)&H1[(mf * 16 + r16) * 264 + wv * 64 + nf * 16 + q * 4] = o;
      }
    }
  };
  auto layer23 = [&]() {           // H1 -> (tanh, x W3) -> Part, mh halves
    #pragma unroll
    for (int mh = 0; mh < 2; ++mh) {
      f32x4 acc[2][2];             // [nf][lm]
      #pragma unroll
      for (int nf = 0; nf < 2; ++nf)
        #pragma unroll
        for (int lm = 0; lm < 2; ++lm) {
          f32x4 c;
          #pragma unroll
          for (int i = 0; i < 4; ++i) c[i] = b2f[nf][i];
          acc[nf][lm] = c;
        }
      #pragma unroll
      for (int ks = 0; ks < 8; ++ks)
        #pragma unroll
        for (int lm = 0; lm < 2; ++lm) {
          bf16x8 hb = *(const bf16x8*)&H1[((mh * 2 + lm) * 16 + r16) * 264 +
                                          ks * 32 + q * 8];
          #pragma unroll
          for (int nf = 0; nf < 2; ++nf)
            acc[nf][lm] = __builtin_amdgcn_mfma_f32_16x16x32_bf16(
                w2f[nf][ks], hb, acc[nf][lm], 0, 0, 0);
        }
      #pragma unroll
      for (int lm = 0; lm < 2; ++lm) {
        float px = 0.f, py = 0.f;
        #pragma unroll
        for (int nf = 0; nf < 2; ++nf)
          #pragma unroll
          for (int i = 0; i < 4; ++i) {
            float tv = fast_tanh(acc[nf][lm][i]);
            px = fmaf(tv, w3v[nf][i].x, px);
            py = fmaf(tv, w3v[nf][i].y, py);
          }
        px += __shfl_xor(px, 16); py += __shfl_xor(py, 16);   // reduce over q
        px += __shfl_xor(px, 32); py += __shfl_xor(py, 32);
        if (q == 0) {
          float2 pr; pr.x = px; pr.y = py;
          *(float2*)&Part[wv][(mh * 2 + lm) * 16 + r16][0] = pr;
        }
      }
    }
  };
  auto finalize = [&](int tile) {  // wave 3: sum 4 partials, sigmoid, store
    if (wv == 3) {
      float2 s0 = *(const float2*)&Part[0][lane][0];
      float2 s1 = *(const float2*)&Part[1][lane][0];
      float2 s2 = *(const float2*)&Part[2][lane][0];
      float2 s3 = *(const float2*)&Part[3][lane][0];
      float sx = (s0.x + s1.x) + (s2.x + s3.x) + b3x;
      float sy = (s0.y + s1.y) + (s2.y + s3.y) + b3y;
      float2 o; o.x = fast_sig(sx); o.y = fast_sig(sy);
      *(float2*)&out[(tile * 64 + lane) * 2] = o;
    }
  };

  // ---- main pipelined loop: CHUNKED tiles (contiguous per block), 2 barriers
  const int b = blockIdx.x;
  int count = tiles_q + (b < tiles_r ? 1 : 0);
  int tile  = b * tiles_q + (b < tiles_r ? b : tiles_r);
  if (count > 0 && tile < total_tiles) {
    GatherRegs gr;
    gather_load(tile, gr);
    gather_write(gr);
    __syncthreads();
    layer1();
    __syncthreads();
    for (;;) {
      const bool more = (count > 1);
      if (more) gather_load(tile + 1, gr);  // contiguous next tile: L2-warm
      layer23();                            // phase A on current tile
      if (more) gather_write(gr);           // Xl(next)
      __syncthreads();
      finalize(tile);                       // phase B: store(tile) + L1(next)
      if (more) layer1();
      if (!more) break;
      __syncthreads();
      ++tile; --count;
    }
  }
}

extern "C" void kernel_launch(void* const* d_in, const int* in_sizes, int n_in,
                              void* d_out, int out_size, void* d_ws, size_t ws_size,
                              hipStream_t stream) {
  (void)d_ws; (void)ws_size; (void)n_in; (void)out_size;
  const float* con  = (const float*)d_in[0];
  const int*   cat2 = (const int*)d_in[1];
  const int*   cat3 = (const int*)d_in[2];
  const int*   cat4 = (const int*)d_in[3];
  const float* emb2 = (const float*)d_in[4];
  const float* emb3 = (const float*)d_in[5];
  const float* emb4 = (const float*)d_in[6];
  const float* W1   = (const float*)d_in[7];
  const float* b1   = (const float*)d_in[8];
  const float* W2   = (const float*)d_in[9];
  const float* b2   = (const float*)d_in[10];
  const float* W3   = (const float*)d_in[11];
  const float* b3   = (const float*)d_in[12];
  float* out = (float*)d_out;

  const int rows  = in_sizes[0] / 6;        // B = 524288
  const int tiles = rows / 64;              // 8192
  const int nblocks = 768;                  // 3 blocks/CU co-resident
  const int tq = tiles / nblocks;           // 10
  const int tr = tiles % nblocks;           // 512

  hipLaunchKernelGGL(mlp_fused, dim3(nblocks), dim3(256), 0, stream,
                     con, cat2, cat3, cat4, emb2, emb3, emb4,
                     W1, b1, W2, b2, W3, b3, out, tiles, tq, tr);
}

// Round 6
// 96.402 us; speedup vs baseline: 1.1380x; 1.1380x over previous
//
#include <hip/hip_runtime.h>
#include <hip/hip_bf16.h>

typedef __attribute__((ext_vector_type(8))) short bf16x8;
typedef __attribute__((ext_vector_type(4))) float f32x4;
typedef __attribute__((ext_vector_type(8))) unsigned short us8;
typedef __attribute__((ext_vector_type(4))) unsigned short us4;
typedef __attribute__((ext_vector_type(2))) unsigned short us2;

#define LOG2E 1.4426950408889634f

__device__ __forceinline__ unsigned short f2bf(float f) {
  union { __hip_bfloat16 h; unsigned short u; } c;
  c.h = __float2bfloat16(f);
  return c.u;
}
__device__ __forceinline__ float fast_tanh(float x) {
  float e = __builtin_amdgcn_exp2f(x * (2.0f * LOG2E));     // e^(2x)
  return 1.0f - 2.0f * __builtin_amdgcn_rcpf(e + 1.0f);
}
__device__ __forceinline__ float fast_sig(float x) {
  return __builtin_amdgcn_rcpf(1.0f + __builtin_amdgcn_exp2f(-LOG2E * x));
}

// Permuted K-layout (W1 rows permuted to match, so gather is pure aligned copies).
// Original features: e2 0-11 | e3 12-29 | e4 30-37 | con 38-43.
// k0-11 e2 | k12-15 con c0-3 (orig 38-41) | k16-23 e3t0+2pad (12-17)
// k24-31 e3t1+2pad (18-23) | k32-39 e3t2+2pad (24-29) | k40-47 e4 (30-37)
// k48-49 con c4,c5 (orig 42-43) | k50 bias(=1.0 row) | k51-63 zero
__device__ __forceinline__ int k2orig(int k) {
  if (k < 12) return k;
  if (k < 16) return 38 + (k - 12);
  if (k < 24) return (k - 16) < 6 ? 12 + (k - 16) : -1;
  if (k < 32) return (k - 24) < 6 ? 18 + (k - 24) : -1;
  if (k < 40) return (k - 32) < 6 ? 24 + (k - 32) : -1;
  if (k < 48) return 30 + (k - 40);
  if (k < 50) return 42 + (k - 48);
  if (k == 50) return 44;                 // bias row marker
  return -1;
}

struct GatherRegs { int i0, i1, i2; float2 c01, c23; };

// launch_bounds (256,2): VGPR cap 256. (256,3) caps at ~170 and SPILLS the
// ~154 persistent weight-fragment regs (R4/R5: WRITE_SIZE 56MB vs 4.2MB out).
__global__ __launch_bounds__(256, 2)
void mlp_fused(const float* __restrict__ con,
               const int* __restrict__ cat2,
               const int* __restrict__ cat3,
               const int* __restrict__ cat4,
               const float* __restrict__ emb2,
               const float* __restrict__ emb3,
               const float* __restrict__ emb4,
               const float* __restrict__ W1, const float* __restrict__ b1,
               const float* __restrict__ W2, const float* __restrict__ b2,
               const float* __restrict__ W3, const float* __restrict__ b3,
               float* __restrict__ out,
               int total_tiles, int tiles_q, int tiles_r)
{
  __shared__ unsigned short embL[128];    // bf16: e2[0,24) e3-padded[24,96) e4[96,128)
  __shared__ unsigned short Xl[64 * 72];  // 64 rows x 64k (+8 pad) bf16
  __shared__ unsigned short H1[64 * 264]; // 64 x 256 (+8) bf16
  __shared__ float Part[4][64][2];        // per-wave layer-3 partials

  const int t    = threadIdx.x;
  const int wv   = t >> 6;
  const int lane = t & 63;
  const int q    = lane >> 4;
  const int r16  = lane & 15;

  // ---- preamble: bf16 tables (e3 rows padded 6->8 with zeros) --------------
  if (t < 24) embL[t] = f2bf(emb2[t]);
  else if (t < 96) { int r = t - 24, g = r >> 3, d = r & 7;
                     embL[t] = (d < 6) ? f2bf(emb3[g * 6 + d]) : 0; }
  else if (t < 128) { int r = t - 96; embL[t] = f2bf(emb4[r]); }
  // constant K region: k50 = 1.0 (bias), k51..63 = 0
  if (t < 64) {
    us2 c2v; c2v[0] = 0x3f80; c2v[1] = 0;
    *(us2*)&Xl[t * 72 + 50] = c2v;
    us4 z4 = {0, 0, 0, 0};       *(us4*)&Xl[t * 72 + 52] = z4;
    us8 z8 = {0, 0, 0, 0, 0, 0, 0, 0}; *(us8*)&Xl[t * 72 + 56] = z8;
  }

  // ---- weight fragments (A-operand = transposed weights), once per block ---
  bf16x8 w1f[4][2];               // L1: n = wv*64 + nf*16 + r16, K=64 (permuted)
  #pragma unroll
  for (int nf = 0; nf < 4; ++nf)
    #pragma unroll
    for (int ks = 0; ks < 2; ++ks) {
      const int n = wv * 64 + nf * 16 + r16;
      bf16x8 w;
      #pragma unroll
      for (int j = 0; j < 8; ++j) {
        const int o = k2orig(ks * 32 + q * 8 + j);
        float v = (o < 0) ? 0.f : ((o == 44) ? b1[n] : W1[o * 256 + n]);
        w[j] = (short)f2bf(v);
      }
      w1f[nf][ks] = w;
    }
  bf16x8 w2f[2][8];               // L2: n = wv*32 + nf*16 + r16, K=256
  #pragma unroll
  for (int nf = 0; nf < 2; ++nf)
    #pragma unroll
    for (int ks = 0; ks < 8; ++ks) {
      const int n = wv * 32 + nf * 16 + r16;
      bf16x8 w;
      #pragma unroll
      for (int j = 0; j < 8; ++j)
        w[j] = (short)f2bf(W2[(ks * 32 + q * 8 + j) * 128 + n]);
      w2f[nf][ks] = w;
    }
  float2 w3v[2][4];               // L3 weights for this lane's h2 features
  #pragma unroll
  for (int nf = 0; nf < 2; ++nf)
    #pragma unroll
    for (int i = 0; i < 4; ++i)
      w3v[nf][i] = *(const float2*)&W3[(wv * 32 + nf * 16 + q * 4 + i) * 2];
  float b2f[2][4];
  #pragma unroll
  for (int nf = 0; nf < 2; ++nf)
    #pragma unroll
    for (int i = 0; i < 4; ++i)
      b2f[nf][i] = b2[wv * 32 + nf * 16 + q * 4 + i];
  const float b3x = b3[0], b3y = b3[1];

  // ---- pipeline helpers -----------------------------------------------------
  auto gather_load = [&](int tile, GatherRegs& gr) {
    const int g = tile * 64 + lane;
    if (wv == 0) {
      gr.i0 = cat2[g * 3]; gr.i1 = cat2[g * 3 + 1]; gr.i2 = cat2[g * 3 + 2];
      gr.c01 = *(const float2*)&con[g * 6];
      gr.c23 = *(const float2*)&con[g * 6 + 2];
    } else if (wv == 1) {
      gr.i0 = cat3[g * 3]; gr.i1 = cat3[g * 3 + 1];
    } else if (wv == 2) {
      gr.i0 = cat3[g * 3 + 2]; gr.i1 = cat4[g];
    } else {
      gr.c01 = *(const float2*)&con[g * 6 + 4];
    }
  };
  auto gather_write = [&](const GatherRegs& gr) {
    unsigned short* xr = &Xl[lane * 72];
    if (wv == 0) {
      *(us4*)&xr[0] = *(const us4*)&embL[gr.i0 * 4];
      *(us4*)&xr[4] = *(const us4*)&embL[8 + gr.i1 * 4];
      *(us4*)&xr[8] = *(const us4*)&embL[16 + gr.i2 * 4];
      us4 c; c[0] = f2bf(gr.c01.x); c[1] = f2bf(gr.c01.y);
             c[2] = f2bf(gr.c23.x); c[3] = f2bf(gr.c23.y);
      *(us4*)&xr[12] = c;
    } else if (wv == 1) {
      *(us8*)&xr[16] = *(const us8*)&embL[24 + gr.i0 * 8];
      *(us8*)&xr[24] = *(const us8*)&embL[48 + gr.i1 * 8];
    } else if (wv == 2) {
      *(us8*)&xr[32] = *(const us8*)&embL[72 + gr.i0 * 8];
      *(us8*)&xr[40] = *(const us8*)&embL[96 + gr.i1 * 8];
    } else {
      us2 c; c[0] = f2bf(gr.c01.x); c[1] = f2bf(gr.c01.y);
      *(us2*)&xr[48] = c;
    }
  };
  auto layer1 = [&]() {            // Xl -> H1 (tanh), mf-sliced for reg pressure
    #pragma unroll
    for (int mf = 0; mf < 4; ++mf) {
      f32x4 acc[4];
      #pragma unroll
      for (int nf = 0; nf < 4; ++nf) acc[nf] = (f32x4){0.f, 0.f, 0.f, 0.f};
      #pragma unroll
      for (int ks = 0; ks < 2; ++ks) {
        bf16x8 xb = *(const bf16x8*)&Xl[(mf * 16 + r16) * 72 + ks * 32 + q * 8];
        #pragma unroll
        for (int nf = 0; nf < 4; ++nf)
          acc[nf] = __builtin_amdgcn_mfma_f32_16x16x32_bf16(
              w1f[nf][ks], xb, acc[nf], 0, 0, 0);
      }
      #pragma unroll
      for (int nf = 0; nf < 4; ++nf) {
        us4 o;
        #pragma unroll
        for (int i = 0; i < 4; ++i) o[i] = f2bf(fast_tanh(acc[nf][i]));
        *(us4*)&H1[(mf * 16 + r16) * 264 + wv * 64 + nf * 16 + q * 4] = o;
      }
    }
  };
  auto layer23 = [&]() {           // H1 -> (tanh, x W3) -> Part, mh halves
    #pragma unroll
    for (int mh = 0; mh < 2; ++mh) {
      f32x4 acc[2][2];             // [nf][lm]
      #pragma unroll
      for (int nf = 0; nf < 2; ++nf)
        #pragma unroll
        for (int lm = 0; lm < 2; ++lm) {
          f32x4 c;
          #pragma unroll
          for (int i = 0; i < 4; ++i) c[i] = b2f[nf][i];
          acc[nf][lm] = c;
        }
      #pragma unroll
      for (int ks = 0; ks < 8; ++ks)
        #pragma unroll
        for (int lm = 0; lm < 2; ++lm) {
          bf16x8 hb = *(const bf16x8*)&H1[((mh * 2 + lm) * 16 + r16) * 264 +
                                          ks * 32 + q * 8];
          #pragma unroll
          for (int nf = 0; nf < 2; ++nf)
            acc[nf][lm] = __builtin_amdgcn_mfma_f32_16x16x32_bf16(
                w2f[nf][ks], hb, acc[nf][lm], 0, 0, 0);
        }
      #pragma unroll
      for (int lm = 0; lm < 2; ++lm) {
        float px = 0.f, py = 0.f;
        #pragma unroll
        for (int nf = 0; nf < 2; ++nf)
          #pragma unroll
          for (int i = 0; i < 4; ++i) {
            float tv = fast_tanh(acc[nf][lm][i]);
            px = fmaf(tv, w3v[nf][i].x, px);
            py = fmaf(tv, w3v[nf][i].y, py);
          }
        px += __shfl_xor(px, 16); py += __shfl_xor(py, 16);   // reduce over q
        px += __shfl_xor(px, 32); py += __shfl_xor(py, 32);
        if (q == 0) {
          float2 pr; pr.x = px; pr.y = py;
          *(float2*)&Part[wv][(mh * 2 + lm) * 16 + r16][0] = pr;
        }
      }
    }
  };
  auto finalize = [&](int tile) {  // wave 3: sum 4 partials, sigmoid, store
    if (wv == 3) {
      float2 s0 = *(const float2*)&Part[0][lane][0];
      float2 s1 = *(const float2*)&Part[1][lane][0];
      float2 s2 = *(const float2*)&Part[2][lane][0];
      float2 s3 = *(const float2*)&Part[3][lane][0];
      float sx = (s0.x + s1.x) + (s2.x + s3.x) + b3x;
      float sy = (s0.y + s1.y) + (s2.y + s3.y) + b3y;
      float2 o; o.x = fast_sig(sx); o.y = fast_sig(sy);
      *(float2*)&out[(tile * 64 + lane) * 2] = o;
    }
  };

  // ---- main pipelined loop: chunked contiguous tiles, 2 barriers/tile ------
  const int b = blockIdx.x;
  int count = tiles_q + (b < tiles_r ? 1 : 0);
  int tile  = b * tiles_q + (b < tiles_r ? b : tiles_r);
  if (count > 0 && tile < total_tiles) {
    GatherRegs gr;
    gather_load(tile, gr);
    gather_write(gr);
    __syncthreads();
    layer1();
    __syncthreads();
    for (;;) {
      const bool more = (count > 1);
      if (more) gather_load(tile + 1, gr);  // global loads in flight over L2
      layer23();                            // phase A on current tile
      if (more) gather_write(gr);           // Xl(next)
      __syncthreads();
      finalize(tile);                       // phase B: store(tile) + L1(next)
      if (more) layer1();
      if (!more) break;
      __syncthreads();
      ++tile; --count;
    }
  }
}

extern "C" void kernel_launch(void* const* d_in, const int* in_sizes, int n_in,
                              void* d_out, int out_size, void* d_ws, size_t ws_size,
                              hipStream_t stream) {
  (void)d_ws; (void)ws_size; (void)n_in; (void)out_size;
  const float* con  = (const float*)d_in[0];
  const int*   cat2 = (const int*)d_in[1];
  const int*   cat3 = (const int*)d_in[2];
  const int*   cat4 = (const int*)d_in[3];
  const float* emb2 = (const float*)d_in[4];
  const float* emb3 = (const float*)d_in[5];
  const float* emb4 = (const float*)d_in[6];
  const float* W1   = (const float*)d_in[7];
  const float* b1   = (const float*)d_in[8];
  const float* W2   = (const float*)d_in[9];
  const float* b2   = (const float*)d_in[10];
  const float* W3   = (const float*)d_in[11];
  const float* b3   = (const float*)d_in[12];
  float* out = (float*)d_out;

  const int rows  = in_sizes[0] / 6;        // B = 524288
  const int tiles = rows / 64;              // 8192
  const int nblocks = 512;                  // 2 blocks/CU co-resident, 16 tiles each
  const int tq = tiles / nblocks;           // 16
  const int tr = tiles % nblocks;           // 0

  hipLaunchKernelGGL(mlp_fused, dim3(nblocks), dim3(256), 0, stream,
                     con, cat2, cat3, cat4, emb2, emb3, emb4,
                     W1, b1, W2, b2, W3, b3, out, tiles, tq, tr);
}